// Round 13
// baseline (150.486 us; speedup 1.0000x reference)
//
#include <hip/hip_runtime.h>

// ---------------------------------------------------------------------------
// VQ-VAE forward, f32, NHWC intermediates (channels innermost -> float4 I/O).
//  K1 conv1 (1->16) co-split (out-ch), 1024 blk P=16 -> y1 [64,128,128,16]
//  K2 bn1 reduce (16 blocks, partials [stat32][4096])
//  K3 conv2 (16->4) co-split (IN-ch quad/lane), 4096 blk, XCD-swizzled -> y2
//  K4 bn2 reduce (4 blocks, partials [8][16384])
//  K5 VQ fused -> h3 [64,64,64,4]
//  K6 loss finalize -> d_out[4194304]
//  K7 convT1-STATS: compute h4 values for bn3 stats ONLY, no store (R12 new)
//  K8 bn3 reduce (16 blocks)
//  K9 convT2-FUSED: recompute h4 tile from h3 in LDS (bias+bn3+relu), then
//     convT2 -> d_out.  Kills the 133 MB h4 write+read round-trip.
// ---------------------------------------------------------------------------

// ---------------- K1: conv1 co-split + per-channel stats (P=16) ------------
__global__ __launch_bounds__(256) void k_conv1(
    const float* __restrict__ x, const float* __restrict__ w1,
    const float* __restrict__ b1, float* __restrict__ y1,
    float* __restrict__ part)
{
  __shared__ float s_w[256];     // [k16][c16]
  __shared__ float s_b[16];
  const int tid = threadIdx.x;
  { int c = tid >> 4, k = tid & 15; s_w[k * 16 + c] = w1[c * 16 + k]; }
  if (tid < 16) s_b[tid] = b1[tid];
  __syncthreads();

  const int lane = tid & 63;
  const int cb = lane & 3;                  // out-channel quad
  const int psl = lane >> 2;                // pixel slot 0..15
  const int gwave = (blockIdx.x << 2) | (tid >> 6);   // 4096 waves
  const int base = gwave << 8;              // 256 pixels per wave
  const int n = base >> 14;
  const float* xb = x + n * 65536;
  const float4* s_w4 = (const float4*)s_w;
  const float4 bv = ((const float4*)s_b)[cb];

  float lsum[4] = {0.f, 0.f, 0.f, 0.f}, lsq[4] = {0.f, 0.f, 0.f, 0.f};

#pragma unroll 1
  for (int i = 0; i < 16; ++i) {
    const int pos = base + (i << 4) + psl;
    const int r = pos & 16383;
    const int oh = r >> 7, ow = r & 127;
    const int ihb = oh * 2 - 1, iwb = ow * 2 - 1;

    float a0 = bv.x, a1 = bv.y, a2 = bv.z, a3 = bv.w;
#pragma unroll
    for (int kh = 0; kh < 4; ++kh) {
      int ih = ihb + kh; bool okh = (unsigned)ih < 256u;
#pragma unroll
      for (int kw = 0; kw < 4; ++kw) {
        int iw = iwb + kw;
        bool ok = okh && ((unsigned)iw < 256u);
        float v = ok ? xb[ih * 256 + iw] : 0.f;
        float4 wv = s_w4[(kh * 4 + kw) * 4 + cb];
        a0 = fmaf(v, wv.x, a0); a1 = fmaf(v, wv.y, a1);
        a2 = fmaf(v, wv.z, a2); a3 = fmaf(v, wv.w, a3);
      }
    }
    *(float4*)(y1 + (size_t)pos * 16 + cb * 4) = make_float4(a0, a1, a2, a3);
    lsum[0] += a0; lsum[1] += a1; lsum[2] += a2; lsum[3] += a3;
    lsq[0] = fmaf(a0, a0, lsq[0]); lsq[1] = fmaf(a1, a1, lsq[1]);
    lsq[2] = fmaf(a2, a2, lsq[2]); lsq[3] = fmaf(a3, a3, lsq[3]);
  }

#pragma unroll
  for (int j = 0; j < 4; ++j) {
    float sv = lsum[j], qv = lsq[j];
#pragma unroll
    for (int d = 4; d < 64; d <<= 1) { sv += __shfl_down(sv, d); qv += __shfl_down(qv, d); }
    if (lane < 4) {
      part[(lane * 4 + j) * 4096 + gwave]      = sv;
      part[(16 + lane * 4 + j) * 4096 + gwave] = qv;
    }
  }
}

// ---------------- BN reduce: NCH blocks, NW per-wave partials --------------
template <int NCH, int NW>
__global__ __launch_bounds__(256) void k_bnredN(
    const float* __restrict__ part, const float* __restrict__ g,
    const float* __restrict__ bt, float* __restrict__ sc,
    float* __restrict__ sh, double invN)
{
  __shared__ double sd[256], sqd[256];
  const int c = blockIdx.x, tid = threadIdx.x;
  const float4* ps = (const float4*)(part + (size_t)c * NW);
  const float4* pq = (const float4*)(part + (size_t)(NCH + c) * NW);
  double S = 0.0, Q = 0.0;
#pragma unroll
  for (int i = 0; i < NW / 1024; ++i) {
    float4 v = ps[i * 256 + tid];
    S += (double)v.x + (double)v.y + (double)v.z + (double)v.w;
    float4 q = pq[i * 256 + tid];
    Q += (double)q.x + (double)q.y + (double)q.z + (double)q.w;
  }
  sd[tid] = S; sqd[tid] = Q;
  __syncthreads();
  for (int off = 128; off > 0; off >>= 1) {
    if (tid < off) { sd[tid] += sd[tid + off]; sqd[tid] += sqd[tid + off]; }
    __syncthreads();
  }
  if (tid == 0) {
    double mean = sd[0] * invN;
    double var  = sqd[0] * invN - mean * mean;
    float scale = (float)((double)g[c] / sqrt(var + 1e-5));
    sc[c] = scale;
    sh[c] = bt[c] - (float)mean * scale;
  }
}

// ---------------- K3: conv2 co-split over INPUT channels -------------------
__global__ __launch_bounds__(256) void k_conv2(
    const float* __restrict__ y1, const float* __restrict__ w2,
    const float* __restrict__ b2, const float* __restrict__ bnp,
    float* __restrict__ y2, float* __restrict__ part)
{
  __shared__ float s_w[1024];        // [k16][ci16][co4]
  __shared__ float s_sc[16], s_sh[16];
  __shared__ float s_b[4];
  const int tid = threadIdx.x;
  for (int i = tid; i < 1024; i += 256) {
    int co = i & 3, ci = (i >> 2) & 15, k = i >> 6;
    int kh = k >> 2, kw = k & 3;
    s_w[i] = w2[((co * 16 + ci) * 4 + kh) * 4 + kw];
  }
  if (tid < 16) { s_sc[tid] = bnp[tid]; s_sh[tid] = bnp[16 + tid]; }
  if (tid < 4)  s_b[tid] = b2[tid];
  __syncthreads();

  // bijective XCD swizzle: grid 4096 = 8 * 512
  const int bid = ((blockIdx.x & 7) << 9) | (blockIdx.x >> 3);
  const int lane = tid & 63;
  const int cb = lane & 3;                 // input-channel quad
  const int psl = lane >> 2;               // pixel slot 0..15
  const int gwave = (bid << 2) | (tid >> 6);   // 16384 waves
  const int pos = (gwave << 4) + psl;          // < 262,144
  const int n = pos >> 12, r = pos & 4095;
  const int oh = r >> 6, ow = r & 63;
  const int ihb = oh * 2 - 1, iwb = ow * 2 - 1;
  const float* yb = y1 + (size_t)n * 262144;
  const float4* s_w4 = (const float4*)s_w;
  const float4 scv = ((const float4*)s_sc)[cb];
  const float4 shv = ((const float4*)s_sh)[cb];

  float acc0 = 0.f, acc1 = 0.f, acc2 = 0.f, acc3 = 0.f;

#pragma unroll
  for (int kh = 0; kh < 4; ++kh) {
    int ih = ihb + kh; bool okh = (unsigned)ih < 128u;
#pragma unroll
    for (int kw = 0; kw < 4; ++kw) {
      int iw = iwb + kw;
      bool ok = okh && ((unsigned)iw < 128u);
      if (ok) {
        float4 v = *(const float4*)(yb + (ih * 128 + iw) * 16 + (cb << 2));
        float a0 = fmaxf(fmaf(v.x, scv.x, shv.x), 0.f);
        float a1 = fmaxf(fmaf(v.y, scv.y, shv.y), 0.f);
        float a2 = fmaxf(fmaf(v.z, scv.z, shv.z), 0.f);
        float a3 = fmaxf(fmaf(v.w, scv.w, shv.w), 0.f);
        int kb = (((kh << 2) | kw) << 4) + (cb << 2);
        float4 w0 = s_w4[kb + 0];
        float4 w1 = s_w4[kb + 1];
        float4 w2v = s_w4[kb + 2];
        float4 w3 = s_w4[kb + 3];
        acc0 = fmaf(a0, w0.x, fmaf(a1, w1.x, fmaf(a2, w2v.x, fmaf(a3, w3.x, acc0))));
        acc1 = fmaf(a0, w0.y, fmaf(a1, w1.y, fmaf(a2, w2v.y, fmaf(a3, w3.y, acc1))));
        acc2 = fmaf(a0, w0.z, fmaf(a1, w1.z, fmaf(a2, w2v.z, fmaf(a3, w3.z, acc2))));
        acc3 = fmaf(a0, w0.w, fmaf(a1, w1.w, fmaf(a2, w2v.w, fmaf(a3, w3.w, acc3))));
      }
    }
  }
  acc0 += __shfl_xor(acc0, 1); acc0 += __shfl_xor(acc0, 2);
  acc1 += __shfl_xor(acc1, 1); acc1 += __shfl_xor(acc1, 2);
  acc2 += __shfl_xor(acc2, 1); acc2 += __shfl_xor(acc2, 2);
  acc3 += __shfl_xor(acc3, 1); acc3 += __shfl_xor(acc3, 2);
  acc0 += s_b[0]; acc1 += s_b[1]; acc2 += s_b[2]; acc3 += s_b[3];

  if (cb == 0)
    *(float4*)(y2 + (size_t)pos * 4) = make_float4(acc0, acc1, acc2, acc3);

  float ls[4] = {acc0, acc1, acc2, acc3};
#pragma unroll
  for (int c = 0; c < 4; ++c) {
    float sv = ls[c], qv = ls[c] * ls[c];
#pragma unroll
    for (int d = 4; d < 64; d <<= 1) { sv += __shfl_down(sv, d); qv += __shfl_down(qv, d); }
    if (lane == 0) {
      part[c * 16384 + gwave]       = sv;
      part[(4 + c) * 16384 + gwave] = qv;
    }
  }
}

// ---------------- K5: fused VQ -------------------------------------------
__global__ __launch_bounds__(256) void k_vq(
    const float* __restrict__ y2, const float* __restrict__ bnp2,
    const float* __restrict__ pw, const float* __restrict__ pb,
    const float* __restrict__ cb, const float* __restrict__ postw,
    const float* __restrict__ postb, float* __restrict__ h3,
    float* __restrict__ lpart)
{
  const int tid = threadIdx.x;
  const int pos = blockIdx.x * 256 + tid;     // < 262,144
  float4 v = *(const float4*)(y2 + (size_t)pos * 4);
  float aa0 = fmaxf(fmaf(v.x, bnp2[0], bnp2[4]), 0.f);
  float aa1 = fmaxf(fmaf(v.y, bnp2[1], bnp2[5]), 0.f);
  float aa2 = fmaxf(fmaf(v.z, bnp2[2], bnp2[6]), 0.f);
  float aa3 = fmaxf(fmaf(v.w, bnp2[3], bnp2[7]), 0.f);
  float z0 = pb[0] + aa0*pw[0] + aa1*pw[1] + aa2*pw[2] + aa3*pw[3];
  float z1 = pb[1] + aa0*pw[4] + aa1*pw[5] + aa2*pw[6] + aa3*pw[7];

  float best = 3.4e38f, q0 = 0.f, q1 = 0.f;
#pragma unroll
  for (int k = 0; k < 3; ++k) {
    float c0 = cb[2 * k], c1 = cb[2 * k + 1];
    float dx = z0 - c0, dy = z1 - c1;
    float d = dx * dx + dy * dy;
    if (d < best) { best = d; q0 = c0; q1 = c1; }   // strict < == first-min
  }
  float dl = (q0 - z0) * (q0 - z0) + (q1 - z1) * (q1 - z1);

  float4 hv;
  hv.x = fmaf(q0, postw[0], fmaf(q1, postw[1], postb[0]));
  hv.y = fmaf(q0, postw[2], fmaf(q1, postw[3], postb[1]));
  hv.z = fmaf(q0, postw[4], fmaf(q1, postw[5], postb[2]));
  hv.w = fmaf(q0, postw[6], fmaf(q1, postw[7], postb[3]));
  *(float4*)(h3 + (size_t)pos * 4) = hv;

  float s = dl;
#pragma unroll
  for (int d = 32; d > 0; d >>= 1) s += __shfl_down(s, d);
  __shared__ float ws4[4];
  if ((tid & 63) == 0) ws4[tid >> 6] = s;
  __syncthreads();
  if (tid == 0) lpart[blockIdx.x] = (ws4[0] + ws4[1]) + (ws4[2] + ws4[3]);
}

__global__ __launch_bounds__(256) void k_lossfin(
    const float* __restrict__ lpart, float* __restrict__ outp)
{
  const int tid = threadIdx.x;
  float s = lpart[tid] + lpart[tid + 256] + lpart[tid + 512] + lpart[tid + 768];
#pragma unroll
  for (int d = 32; d > 0; d >>= 1) s += __shfl_down(s, d);
  __shared__ float ws4[4];
  if ((tid & 63) == 0) ws4[tid >> 6] = s;
  __syncthreads();
  if (tid == 0) {
    double tot = (double)ws4[0] + (double)ws4[1] + (double)ws4[2] + (double)ws4[3];
    outp[0] = (float)(1.2 * tot / 524288.0);   // (1+BETA) * mean over B*N*C
  }
}

// ---------------- K7: convT1 STATS-ONLY (no h4 store) ----------------------
__global__ __launch_bounds__(256) void k_convt1s(
    const float* __restrict__ h3, const float* __restrict__ w,
    const float* __restrict__ bias, float* __restrict__ part)
{
  __shared__ float s_w[1024];   // [k16][ci4][co16]
  __shared__ float s_b[16];
  const int tid = threadIdx.x;
  for (int i = tid; i < 1024; i += 256) {
    int co = i & 15, ci = (i >> 4) & 3, k = i >> 6;
    int kh = k >> 2, kw = k & 3;
    s_w[i] = w[((co * 4 + ci) * 4 + kh) * 4 + kw];
  }
  if (tid < 16) s_b[tid] = bias[tid];
  __syncthreads();

  const int lane = tid & 63;
  const int cb = lane & 3;
  const int psl = lane >> 2;
  const int gwave = (blockIdx.x << 2) | (tid >> 6);   // 4096 waves
  const int base = gwave << 8;
  const int n = base >> 14;
  const float* hb = h3 + (size_t)n * 16384;
  const float4* s_w4 = (const float4*)s_w;
  const float4 bv = ((const float4*)s_b)[cb];

  float lsum[4] = {0.f, 0.f, 0.f, 0.f}, lsq[4] = {0.f, 0.f, 0.f, 0.f};

#pragma unroll 1
  for (int i = 0; i < 16; ++i) {
    const int pos = base + (i << 4) + psl;
    const int r = pos & 16383;
    const int oh = r >> 7, ow = r & 127;
    const int ohp = oh & 1, owp = ow & 1;

    float a0 = bv.x, a1 = bv.y, a2 = bv.z, a3 = bv.w;
#pragma unroll
    for (int th = 0; th < 2; ++th) {
      int kh = th * 2 + ohp;
      int ih = (oh + kh - 2) >> 1;
      bool okh = (unsigned)ih < 64u;
#pragma unroll
      for (int tw = 0; tw < 2; ++tw) {
        int kw = tw * 2 + owp;
        int iw = (ow + kw - 2) >> 1;
        bool ok = okh && ((unsigned)iw < 64u);
        if (ok) {
          float4 v = *(const float4*)(hb + (ih * 64 + iw) * 4);
          int k16 = (kh * 4 + kw) * 16;
          float4 w0 = s_w4[k16 + 0 * 4 + cb];
          float4 w1 = s_w4[k16 + 1 * 4 + cb];
          float4 w2 = s_w4[k16 + 2 * 4 + cb];
          float4 w3 = s_w4[k16 + 3 * 4 + cb];
          a0 = fmaf(v.x, w0.x, fmaf(v.y, w1.x, fmaf(v.z, w2.x, fmaf(v.w, w3.x, a0))));
          a1 = fmaf(v.x, w0.y, fmaf(v.y, w1.y, fmaf(v.z, w2.y, fmaf(v.w, w3.y, a1))));
          a2 = fmaf(v.x, w0.z, fmaf(v.y, w1.z, fmaf(v.z, w2.z, fmaf(v.w, w3.z, a2))));
          a3 = fmaf(v.x, w0.w, fmaf(v.y, w1.w, fmaf(v.z, w2.w, fmaf(v.w, w3.w, a3))));
        }
      }
    }
    lsum[0] += a0; lsum[1] += a1; lsum[2] += a2; lsum[3] += a3;
    lsq[0] = fmaf(a0, a0, lsq[0]); lsq[1] = fmaf(a1, a1, lsq[1]);
    lsq[2] = fmaf(a2, a2, lsq[2]); lsq[3] = fmaf(a3, a3, lsq[3]);
  }

#pragma unroll
  for (int j = 0; j < 4; ++j) {
    float sv = lsum[j], qv = lsq[j];
#pragma unroll
    for (int d = 4; d < 64; d <<= 1) { sv += __shfl_down(sv, d); qv += __shfl_down(qv, d); }
    if (lane < 4) {
      part[(lane * 4 + j) * 4096 + gwave]      = sv;
      part[(16 + lane * 4 + j) * 4096 + gwave] = qv;
    }
  }
}

// ---------------- K9: convT2 FUSED (recompute h4 tile from h3) -------------
// Block = (n, 16x16 h4-tile). Stage 11x11x4 h3 patch (guarded), recompute the
// 18x18x16 h4 tile in LDS with bias+bn3+relu, then convT2 second half.
__global__ __launch_bounds__(256) void k_convt2f(
    const float* __restrict__ h3, const float* __restrict__ w1,
    const float* __restrict__ b1, const float* __restrict__ w2,
    const float* __restrict__ bias2, const float* __restrict__ bnp,
    float* __restrict__ out)
{
  __shared__ float4 s_h3[11][12];
  __shared__ float4 s_t[4][18][19];
  __shared__ float s_w1[1024];   // [k16][ci4][co16]
  __shared__ float s_w2[256];    // [ci16][kh4][kw4]
  __shared__ float s_b1[16];
  const int tid = threadIdx.x;
  for (int i = tid; i < 1024; i += 256) {
    int co = i & 15, ci = (i >> 4) & 3, k = i >> 6;
    int kh = k >> 2, kw = k & 3;
    s_w1[i] = w1[((co * 4 + ci) * 4 + kh) * 4 + kw];
  }
  s_w2[tid] = w2[tid];
  if (tid < 16) s_b1[tid] = b1[tid];

  // bijective XCD swizzle: grid 4096 = 8 * 512
  const int bx = ((blockIdx.x & 7) << 9) | (blockIdx.x >> 3);
  const int n = bx >> 6;
  const int tile = bx & 63;
  const int ta = ((tile >> 3) << 4);
  const int tb = ((tile & 7) << 4);
  const int hrow0 = (ta >> 1) - 2, hcol0 = (tb >> 1) - 2;
  const float* hb = h3 + (size_t)n * 16384;

  // stage h3 patch (121 float4), guarded -> zeros outside [0,64)
  if (tid < 121) {
    int pr = tid / 11, pc = tid - pr * 11;
    int sr = hrow0 + pr, sc = hcol0 + pc;
    float4 t = make_float4(0.f, 0.f, 0.f, 0.f);
    if (((unsigned)sr < 64u) && ((unsigned)sc < 64u))
      t = *(const float4*)(hb + (sr * 64 + sc) * 4);
    s_h3[pr][pc] = t;
  }
  __syncthreads();

  const float4* s_w14 = (const float4*)s_w1;
  const float4* s_b14 = (const float4*)s_b1;

  // recompute h4 tile: 1296 (pos, co-quad) units
  for (int i = tid; i < 1296; i += 256) {
    int g = i & 3, p = i >> 2;
    int row = p / 18, col = p - row * 18;
    int ih = ta - 1 + row, iw = tb - 1 + col;
    float4 t = make_float4(0.f, 0.f, 0.f, 0.f);
    if (((unsigned)ih < 128u) && ((unsigned)iw < 128u)) {
      t = s_b14[g];
      const int ohp = ih & 1, owp = iw & 1;
#pragma unroll
      for (int th = 0; th < 2; ++th) {
        int kh = th * 2 + ohp;
        int lr = ((ih + kh - 2) >> 1) - hrow0;
#pragma unroll
        for (int tw = 0; tw < 2; ++tw) {
          int kw = tw * 2 + owp;
          int lc = ((iw + kw - 2) >> 1) - hcol0;
          float4 hv = s_h3[lr][lc];
          int k16 = ((kh << 2) | kw) << 4;
          float4 w0 = s_w14[k16 + 0 + g];
          float4 w1v = s_w14[k16 + 4 + g];
          float4 w2v = s_w14[k16 + 8 + g];
          float4 w3v = s_w14[k16 + 12 + g];
          t.x = fmaf(hv.x, w0.x, fmaf(hv.y, w1v.x, fmaf(hv.z, w2v.x, fmaf(hv.w, w3v.x, t.x))));
          t.y = fmaf(hv.x, w0.y, fmaf(hv.y, w1v.y, fmaf(hv.z, w2v.y, fmaf(hv.w, w3v.y, t.y))));
          t.z = fmaf(hv.x, w0.z, fmaf(hv.y, w1v.z, fmaf(hv.z, w2v.z, fmaf(hv.w, w3v.z, t.z))));
          t.w = fmaf(hv.x, w0.w, fmaf(hv.y, w1v.w, fmaf(hv.z, w2v.w, fmaf(hv.w, w3v.w, t.w))));
        }
      }
      float4 scv = *(const float4*)(bnp + 40 + (g << 2));
      float4 shv = *(const float4*)(bnp + 56 + (g << 2));
      t.x = fmaxf(fmaf(t.x, scv.x, shv.x), 0.f);
      t.y = fmaxf(fmaf(t.y, scv.y, shv.y), 0.f);
      t.z = fmaxf(fmaf(t.z, scv.z, shv.z), 0.f);
      t.w = fmaxf(fmaf(t.w, scv.w, shv.w), 0.f);
    }
    s_t[g][row][col] = t;
  }
  __syncthreads();

  const int a = tid >> 4, b = tid & 15;
  const float4* s_w4 = (const float4*)s_w2;
  float acc00 = 0.f, acc01 = 0.f, acc10 = 0.f, acc11 = 0.f;

#pragma unroll
  for (int g = 0; g < 4; ++g) {
    float4 v00 = s_t[g][a  ][b  ], v01 = s_t[g][a  ][b+1], v02 = s_t[g][a  ][b+2];
    float4 v10 = s_t[g][a+1][b  ], v11 = s_t[g][a+1][b+1], v12 = s_t[g][a+1][b+2];
    float4 v20 = s_t[g][a+2][b  ], v21 = s_t[g][a+2][b+1], v22 = s_t[g][a+2][b+2];
#pragma unroll
    for (int j = 0; j < 4; ++j) {
      int ci = g * 4 + j;
      float4 r0 = s_w4[ci*4+0], r1 = s_w4[ci*4+1];
      float4 r2 = s_w4[ci*4+2], r3 = s_w4[ci*4+3];
      float a00 = (j==0)?v00.x:(j==1)?v00.y:(j==2)?v00.z:v00.w;
      float a01 = (j==0)?v01.x:(j==1)?v01.y:(j==2)?v01.z:v01.w;
      float a02 = (j==0)?v02.x:(j==1)?v02.y:(j==2)?v02.z:v02.w;
      float a10 = (j==0)?v10.x:(j==1)?v10.y:(j==2)?v10.z:v10.w;
      float a11 = (j==0)?v11.x:(j==1)?v11.y:(j==2)?v11.z:v11.w;
      float a12 = (j==0)?v12.x:(j==1)?v12.y:(j==2)?v12.z:v12.w;
      float a20 = (j==0)?v20.x:(j==1)?v20.y:(j==2)?v20.z:v20.w;
      float a21 = (j==0)?v21.x:(j==1)?v21.y:(j==2)?v21.z:v21.w;
      float a22 = (j==0)?v22.x:(j==1)?v22.y:(j==2)?v22.z:v22.w;
      acc00 += a00*r0.x + a01*r0.z + a10*r2.x + a11*r2.z;
      acc01 += a01*r0.y + a02*r0.w + a11*r2.y + a12*r2.w;
      acc10 += a10*r1.x + a11*r1.z + a20*r3.x + a21*r3.z;
      acc11 += a11*r1.y + a12*r1.w + a21*r3.y + a22*r3.w;
    }
  }
  const float bv = bias2[0];
  const int A = ta + a, B = tb + b;
  float* ob = out + n * 65536 + (2 * A) * 256 + 2 * B;
  *(float2*)ob         = make_float2(acc00 + bv, acc01 + bv);
  *(float2*)(ob + 256) = make_float2(acc10 + bv, acc11 + bv);
}

// ---------------------------------------------------------------------------
extern "C" void kernel_launch(void* const* d_in, const int* in_sizes, int n_in,
                              void* d_out, int out_size, void* d_ws, size_t ws_size,
                              hipStream_t stream)
{
  const float* x      = (const float*)d_in[0];
  const float* enc_w1 = (const float*)d_in[1];
  const float* enc_b1 = (const float*)d_in[2];
  const float* bn1_g  = (const float*)d_in[3];
  const float* bn1_b  = (const float*)d_in[4];
  const float* enc_w2 = (const float*)d_in[5];
  const float* enc_b2 = (const float*)d_in[6];
  const float* bn2_g  = (const float*)d_in[7];
  const float* bn2_b  = (const float*)d_in[8];
  const float* pre_w  = (const float*)d_in[9];
  const float* pre_b  = (const float*)d_in[10];
  const float* cb     = (const float*)d_in[11];
  const float* post_w = (const float*)d_in[12];
  const float* post_b = (const float*)d_in[13];
  const float* dec_w1 = (const float*)d_in[14];
  const float* dec_b1 = (const float*)d_in[15];
  const float* bn3_g  = (const float*)d_in[16];
  const float* bn3_b  = (const float*)d_in[17];
  const float* dec_w2 = (const float*)d_in[18];
  const float* dec_b2 = (const float*)d_in[19];

  float* ws  = (float*)d_ws;
  float* y1  = ws;                       // 16,777,216 f (NHWC)
  float* y2  = ws + 16777216;            //  1,048,576 f
  float* h3  = ws + 17825792;            //  1,048,576 f
  float* p1  = ws + 18874368;            //    131,072 f ([32][4096]) -- also p3
  float* p2  = ws + 19005440;            //    131,072 f ([8][16384])
  float* lp  = ws + 19136512;            //      1,024 f
  float* bnp = ws + 19137536;            //         72 f (sc1,sh1,sc2,sh2,sc3,sh3)
  float* p3  = p1;
  float* out = (float*)d_out;

  k_conv1<<<1024, 256, 0, stream>>>(x, enc_w1, enc_b1, y1, p1);
  k_bnredN<16, 4096><<<16, 256, 0, stream>>>(p1, bn1_g, bn1_b, bnp, bnp + 16, 1.0 / 1048576.0);
  k_conv2<<<4096, 256, 0, stream>>>(y1, enc_w2, enc_b2, bnp, y2, p2);
  k_bnredN<4, 16384><<<4, 256, 0, stream>>>(p2, bn2_g, bn2_b, bnp + 32, bnp + 36, 1.0 / 262144.0);
  k_vq<<<1024, 256, 0, stream>>>(y2, bnp + 32, pre_w, pre_b, cb, post_w, post_b, h3, lp);
  k_lossfin<<<1, 256, 0, stream>>>(lp, out + 4194304);
  k_convt1s<<<1024, 256, 0, stream>>>(h3, dec_w1, dec_b1, p3);
  k_bnredN<16, 4096><<<16, 256, 0, stream>>>(p3, bn3_g, bn3_b, bnp + 40, bnp + 56, 1.0 / 1048576.0);
  k_convt2f<<<4096, 256, 0, stream>>>(h3, dec_w1, dec_b1, dec_w2, dec_b2, bnp, out);
}

// Round 14
// 136.017 us; speedup vs baseline: 1.1064x; 1.1064x over previous
//
#include <hip/hip_runtime.h>

// ---------------------------------------------------------------------------
// VQ-VAE forward, f32, NHWC intermediates (channels innermost -> float4 I/O).
//  K1 conv1 (1->16) co-split + LDS-staged x patch (R14 new) -> y1
//  K2 bn1 reduce (16 blocks, partials [stat32][4096])
//  K3 conv2 (16->4) co-split (IN-ch quad/lane), XCD-swizzled -> y2
//  K4 bn2 reduce (4 blocks, partials [8][16384])
//  K5 VQ fused -> h3
//  K6 loss finalize -> d_out[4194304]
//  K7 convT1 (4->16) co-split + LDS-staged h3 patch (R14 new) -> h4
//  K8 bn3 reduce (16 blocks)
//  K9 convT2 (16->1), LDS-tiled, XCD-swizzled -> d_out
// R13 lesson: h4 recompute-fusion lost (recompute tax + 11.7M bank conflicts
// + 27% occ > 133MB traffic win) -> reverted. This round: kill the latency
// bottleneck in conv1/convt1 via SINGLE-PASS LDS staging (R7's failure was
// multi-pass re-staging; this is one pass, all channels).
// ---------------------------------------------------------------------------

// ---------------- K1: conv1, x staged in LDS, co-split, stats --------------
// Block = one image x 8 output rows (1024 px). Stage 18x258 x-patch once.
__global__ __launch_bounds__(256) void k_conv1(
    const float* __restrict__ x, const float* __restrict__ w1,
    const float* __restrict__ b1, float* __restrict__ y1,
    float* __restrict__ part)
{
  __shared__ float s_x[18 * 260];    // rows 18, stride 260, cols 0..257 used
  __shared__ float s_w[256];         // [k16][c16]
  __shared__ float s_b[16];
  const int tid = threadIdx.x;
  { int c = tid >> 4, k = tid & 15; s_w[k * 16 + c] = w1[c * 16 + k]; }
  if (tid < 16) s_b[tid] = b1[tid];

  const int n  = blockIdx.x >> 4;          // 16 row-blocks per image
  const int rb = blockIdx.x & 15;
  const int ih0 = (rb << 4) - 1;           // input row origin
  const float* xb = x + n * 65536;

  for (int j = tid; j < 4644; j += 256) {  // 18 * 258
    int rr = j / 258, c = j - rr * 258;
    int ih = ih0 + rr, iw = c - 1;
    float v = 0.f;
    if (((unsigned)ih < 256u) && ((unsigned)iw < 256u)) v = xb[ih * 256 + iw];
    s_x[rr * 260 + c] = v;
  }
  __syncthreads();

  const int lane = tid & 63;
  const int cb = lane & 3;                 // out-channel quad
  const int psl = lane >> 2;               // pixel slot 0..15
  const int gwave = (blockIdx.x << 2) | (tid >> 6);   // 4096 waves
  const int base = gwave << 8;             // 256 consecutive pixels per wave
  const float4* s_w4 = (const float4*)s_w;
  const float4 bv = ((const float4*)s_b)[cb];

  float lsum[4] = {0.f, 0.f, 0.f, 0.f}, lsq[4] = {0.f, 0.f, 0.f, 0.f};

#pragma unroll 1
  for (int i = 0; i < 16; ++i) {
    const int pos = base + (i << 4) + psl;
    const int r = pos & 16383;
    const int oh = r >> 7, ow = r & 127;
    const int lr2 = (oh - (rb << 3)) << 1;     // 2 * local output row

    float a0 = bv.x, a1 = bv.y, a2 = bv.z, a3 = bv.w;
#pragma unroll
    for (int kh = 0; kh < 4; ++kh) {
      const float* rowp = s_x + (lr2 + kh) * 260 + (ow << 1);
#pragma unroll
      for (int kw = 0; kw < 4; ++kw) {
        float v = rowp[kw];
        float4 wv = s_w4[(kh * 4 + kw) * 4 + cb];
        a0 = fmaf(v, wv.x, a0); a1 = fmaf(v, wv.y, a1);
        a2 = fmaf(v, wv.z, a2); a3 = fmaf(v, wv.w, a3);
      }
    }
    *(float4*)(y1 + (size_t)pos * 16 + cb * 4) = make_float4(a0, a1, a2, a3);
    lsum[0] += a0; lsum[1] += a1; lsum[2] += a2; lsum[3] += a3;
    lsq[0] = fmaf(a0, a0, lsq[0]); lsq[1] = fmaf(a1, a1, lsq[1]);
    lsq[2] = fmaf(a2, a2, lsq[2]); lsq[3] = fmaf(a3, a3, lsq[3]);
  }

#pragma unroll
  for (int j = 0; j < 4; ++j) {
    float sv = lsum[j], qv = lsq[j];
#pragma unroll
    for (int d = 4; d < 64; d <<= 1) { sv += __shfl_down(sv, d); qv += __shfl_down(qv, d); }
    if (lane < 4) {
      part[(lane * 4 + j) * 4096 + gwave]      = sv;
      part[(16 + lane * 4 + j) * 4096 + gwave] = qv;
    }
  }
}

// ---------------- BN reduce: NCH blocks, NW per-wave partials --------------
template <int NCH, int NW>
__global__ __launch_bounds__(256) void k_bnredN(
    const float* __restrict__ part, const float* __restrict__ g,
    const float* __restrict__ bt, float* __restrict__ sc,
    float* __restrict__ sh, double invN)
{
  __shared__ double sd[256], sqd[256];
  const int c = blockIdx.x, tid = threadIdx.x;
  const float4* ps = (const float4*)(part + (size_t)c * NW);
  const float4* pq = (const float4*)(part + (size_t)(NCH + c) * NW);
  double S = 0.0, Q = 0.0;
#pragma unroll
  for (int i = 0; i < NW / 1024; ++i) {
    float4 v = ps[i * 256 + tid];
    S += (double)v.x + (double)v.y + (double)v.z + (double)v.w;
    float4 q = pq[i * 256 + tid];
    Q += (double)q.x + (double)q.y + (double)q.z + (double)q.w;
  }
  sd[tid] = S; sqd[tid] = Q;
  __syncthreads();
  for (int off = 128; off > 0; off >>= 1) {
    if (tid < off) { sd[tid] += sd[tid + off]; sqd[tid] += sqd[tid + off]; }
    __syncthreads();
  }
  if (tid == 0) {
    double mean = sd[0] * invN;
    double var  = sqd[0] * invN - mean * mean;
    float scale = (float)((double)g[c] / sqrt(var + 1e-5));
    sc[c] = scale;
    sh[c] = bt[c] - (float)mean * scale;
  }
}

// ---------------- K3: conv2 co-split over INPUT channels (R11-proven) ------
__global__ __launch_bounds__(256) void k_conv2(
    const float* __restrict__ y1, const float* __restrict__ w2,
    const float* __restrict__ b2, const float* __restrict__ bnp,
    float* __restrict__ y2, float* __restrict__ part)
{
  __shared__ float s_w[1024];        // [k16][ci16][co4]
  __shared__ float s_sc[16], s_sh[16];
  __shared__ float s_b[4];
  const int tid = threadIdx.x;
  for (int i = tid; i < 1024; i += 256) {
    int co = i & 3, ci = (i >> 2) & 15, k = i >> 6;
    int kh = k >> 2, kw = k & 3;
    s_w[i] = w2[((co * 16 + ci) * 4 + kh) * 4 + kw];
  }
  if (tid < 16) { s_sc[tid] = bnp[tid]; s_sh[tid] = bnp[16 + tid]; }
  if (tid < 4)  s_b[tid] = b2[tid];
  __syncthreads();

  // bijective XCD swizzle: grid 4096 = 8 * 512
  const int bid = ((blockIdx.x & 7) << 9) | (blockIdx.x >> 3);
  const int lane = tid & 63;
  const int cb = lane & 3;                 // input-channel quad
  const int psl = lane >> 2;               // pixel slot 0..15
  const int gwave = (bid << 2) | (tid >> 6);   // 16384 waves
  const int pos = (gwave << 4) + psl;          // < 262,144
  const int n = pos >> 12, r = pos & 4095;
  const int oh = r >> 6, ow = r & 63;
  const int ihb = oh * 2 - 1, iwb = ow * 2 - 1;
  const float* yb = y1 + (size_t)n * 262144;
  const float4* s_w4 = (const float4*)s_w;
  const float4 scv = ((const float4*)s_sc)[cb];
  const float4 shv = ((const float4*)s_sh)[cb];

  float acc0 = 0.f, acc1 = 0.f, acc2 = 0.f, acc3 = 0.f;

#pragma unroll
  for (int kh = 0; kh < 4; ++kh) {
    int ih = ihb + kh; bool okh = (unsigned)ih < 128u;
#pragma unroll
    for (int kw = 0; kw < 4; ++kw) {
      int iw = iwb + kw;
      bool ok = okh && ((unsigned)iw < 128u);
      if (ok) {
        float4 v = *(const float4*)(yb + (ih * 128 + iw) * 16 + (cb << 2));
        float a0 = fmaxf(fmaf(v.x, scv.x, shv.x), 0.f);
        float a1 = fmaxf(fmaf(v.y, scv.y, shv.y), 0.f);
        float a2 = fmaxf(fmaf(v.z, scv.z, shv.z), 0.f);
        float a3 = fmaxf(fmaf(v.w, scv.w, shv.w), 0.f);
        int kb = (((kh << 2) | kw) << 4) + (cb << 2);
        float4 w0 = s_w4[kb + 0];
        float4 w1 = s_w4[kb + 1];
        float4 w2v = s_w4[kb + 2];
        float4 w3 = s_w4[kb + 3];
        acc0 = fmaf(a0, w0.x, fmaf(a1, w1.x, fmaf(a2, w2v.x, fmaf(a3, w3.x, acc0))));
        acc1 = fmaf(a0, w0.y, fmaf(a1, w1.y, fmaf(a2, w2v.y, fmaf(a3, w3.y, acc1))));
        acc2 = fmaf(a0, w0.z, fmaf(a1, w1.z, fmaf(a2, w2v.z, fmaf(a3, w3.z, acc2))));
        acc3 = fmaf(a0, w0.w, fmaf(a1, w1.w, fmaf(a2, w2v.w, fmaf(a3, w3.w, acc3))));
      }
    }
  }
  acc0 += __shfl_xor(acc0, 1); acc0 += __shfl_xor(acc0, 2);
  acc1 += __shfl_xor(acc1, 1); acc1 += __shfl_xor(acc1, 2);
  acc2 += __shfl_xor(acc2, 1); acc2 += __shfl_xor(acc2, 2);
  acc3 += __shfl_xor(acc3, 1); acc3 += __shfl_xor(acc3, 2);
  acc0 += s_b[0]; acc1 += s_b[1]; acc2 += s_b[2]; acc3 += s_b[3];

  if (cb == 0)
    *(float4*)(y2 + (size_t)pos * 4) = make_float4(acc0, acc1, acc2, acc3);

  float ls[4] = {acc0, acc1, acc2, acc3};
#pragma unroll
  for (int c = 0; c < 4; ++c) {
    float sv = ls[c], qv = ls[c] * ls[c];
#pragma unroll
    for (int d = 4; d < 64; d <<= 1) { sv += __shfl_down(sv, d); qv += __shfl_down(qv, d); }
    if (lane == 0) {
      part[c * 16384 + gwave]       = sv;
      part[(4 + c) * 16384 + gwave] = qv;
    }
  }
}

// ---------------- K5: fused VQ -------------------------------------------
__global__ __launch_bounds__(256) void k_vq(
    const float* __restrict__ y2, const float* __restrict__ bnp2,
    const float* __restrict__ pw, const float* __restrict__ pb,
    const float* __restrict__ cb, const float* __restrict__ postw,
    const float* __restrict__ postb, float* __restrict__ h3,
    float* __restrict__ lpart)
{
  const int tid = threadIdx.x;
  const int pos = blockIdx.x * 256 + tid;     // < 262,144
  float4 v = *(const float4*)(y2 + (size_t)pos * 4);
  float aa0 = fmaxf(fmaf(v.x, bnp2[0], bnp2[4]), 0.f);
  float aa1 = fmaxf(fmaf(v.y, bnp2[1], bnp2[5]), 0.f);
  float aa2 = fmaxf(fmaf(v.z, bnp2[2], bnp2[6]), 0.f);
  float aa3 = fmaxf(fmaf(v.w, bnp2[3], bnp2[7]), 0.f);
  float z0 = pb[0] + aa0*pw[0] + aa1*pw[1] + aa2*pw[2] + aa3*pw[3];
  float z1 = pb[1] + aa0*pw[4] + aa1*pw[5] + aa2*pw[6] + aa3*pw[7];

  float best = 3.4e38f, q0 = 0.f, q1 = 0.f;
#pragma unroll
  for (int k = 0; k < 3; ++k) {
    float c0 = cb[2 * k], c1 = cb[2 * k + 1];
    float dx = z0 - c0, dy = z1 - c1;
    float d = dx * dx + dy * dy;
    if (d < best) { best = d; q0 = c0; q1 = c1; }   // strict < == first-min
  }
  float dl = (q0 - z0) * (q0 - z0) + (q1 - z1) * (q1 - z1);

  float4 hv;
  hv.x = fmaf(q0, postw[0], fmaf(q1, postw[1], postb[0]));
  hv.y = fmaf(q0, postw[2], fmaf(q1, postw[3], postb[1]));
  hv.z = fmaf(q0, postw[4], fmaf(q1, postw[5], postb[2]));
  hv.w = fmaf(q0, postw[6], fmaf(q1, postw[7], postb[3]));
  *(float4*)(h3 + (size_t)pos * 4) = hv;

  float s = dl;
#pragma unroll
  for (int d = 32; d > 0; d >>= 1) s += __shfl_down(s, d);
  __shared__ float ws4[4];
  if ((tid & 63) == 0) ws4[tid >> 6] = s;
  __syncthreads();
  if (tid == 0) lpart[blockIdx.x] = (ws4[0] + ws4[1]) + (ws4[2] + ws4[3]);
}

__global__ __launch_bounds__(256) void k_lossfin(
    const float* __restrict__ lpart, float* __restrict__ outp)
{
  const int tid = threadIdx.x;
  float s = lpart[tid] + lpart[tid + 256] + lpart[tid + 512] + lpart[tid + 768];
#pragma unroll
  for (int d = 32; d > 0; d >>= 1) s += __shfl_down(s, d);
  __shared__ float ws4[4];
  if ((tid & 63) == 0) ws4[tid >> 6] = s;
  __syncthreads();
  if (tid == 0) {
    double tot = (double)ws4[0] + (double)ws4[1] + (double)ws4[2] + (double)ws4[3];
    outp[0] = (float)(1.2 * tot / 524288.0);   // (1+BETA) * mean over B*N*C
  }
}

// ---------------- K7: convT1 (4->16), h3 staged in LDS, co-split -----------
// Block = one image x 8 output rows (1024 px). Stage 6x66 float4 h3-patch.
__global__ __launch_bounds__(256) void k_convt1(
    const float* __restrict__ h3, const float* __restrict__ w,
    const float* __restrict__ bias, float* __restrict__ h4,
    float* __restrict__ part)
{
  __shared__ float4 s_h[6 * 68];     // 6 rows, stride 68, cols 0..65 used
  __shared__ float s_w[1024];        // [k16][ci4][co16]
  __shared__ float s_b[16];
  const int tid = threadIdx.x;
  for (int i = tid; i < 1024; i += 256) {
    int co = i & 15, ci = (i >> 4) & 3, k = i >> 6;
    int kh = k >> 2, kw = k & 3;
    s_w[i] = w[((co * 4 + ci) * 4 + kh) * 4 + kw];
  }
  if (tid < 16) s_b[tid] = bias[tid];

  const int n  = blockIdx.x >> 4;
  const int rb = blockIdx.x & 15;
  const int row0 = (rb << 2) - 1;          // h3 row origin
  const float* hb = h3 + (size_t)n * 16384;

  for (int j = tid; j < 396; j += 256) {   // 6 * 66
    int rr = j / 66, c = j - rr * 66;
    int sr = row0 + rr, sc = c - 1;
    float4 t = make_float4(0.f, 0.f, 0.f, 0.f);
    if (((unsigned)sr < 64u) && ((unsigned)sc < 64u))
      t = *(const float4*)(hb + (sr * 64 + sc) * 4);
    s_h[rr * 68 + c] = t;
  }
  __syncthreads();

  const int lane = tid & 63;
  const int cb = lane & 3;
  const int psl = lane >> 2;
  const int gwave = (blockIdx.x << 2) | (tid >> 6);   // 4096 waves
  const int base = gwave << 8;
  const float4* s_w4 = (const float4*)s_w;   // idx = k*16 + ci*4 + cb
  const float4 bv = ((const float4*)s_b)[cb];

  float lsum[4] = {0.f, 0.f, 0.f, 0.f}, lsq[4] = {0.f, 0.f, 0.f, 0.f};

#pragma unroll 1
  for (int i = 0; i < 16; ++i) {
    const int pos = base + (i << 4) + psl;
    const int r = pos & 16383;
    const int oh = r >> 7, ow = r & 127;
    const int ohp = oh & 1, owp = ow & 1;

    float a0 = bv.x, a1 = bv.y, a2 = bv.z, a3 = bv.w;
#pragma unroll
    for (int th = 0; th < 2; ++th) {
      int kh = th * 2 + ohp;
      int lih = ((oh + kh - 2) >> 1) - row0;
#pragma unroll
      for (int tw = 0; tw < 2; ++tw) {
        int kw = tw * 2 + owp;
        int liw = ((ow + kw - 2) >> 1) + 1;
        float4 v = s_h[lih * 68 + liw];
        int k16 = (kh * 4 + kw) * 16;
        float4 w0 = s_w4[k16 + 0 * 4 + cb];
        float4 w1 = s_w4[k16 + 1 * 4 + cb];
        float4 w2 = s_w4[k16 + 2 * 4 + cb];
        float4 w3 = s_w4[k16 + 3 * 4 + cb];
        a0 = fmaf(v.x, w0.x, fmaf(v.y, w1.x, fmaf(v.z, w2.x, fmaf(v.w, w3.x, a0))));
        a1 = fmaf(v.x, w0.y, fmaf(v.y, w1.y, fmaf(v.z, w2.y, fmaf(v.w, w3.y, a1))));
        a2 = fmaf(v.x, w0.z, fmaf(v.y, w1.z, fmaf(v.z, w2.z, fmaf(v.w, w3.z, a2))));
        a3 = fmaf(v.x, w0.w, fmaf(v.y, w1.w, fmaf(v.z, w2.w, fmaf(v.w, w3.w, a3))));
      }
    }
    *(float4*)(h4 + (size_t)pos * 16 + cb * 4) = make_float4(a0, a1, a2, a3);
    lsum[0] += a0; lsum[1] += a1; lsum[2] += a2; lsum[3] += a3;
    lsq[0] = fmaf(a0, a0, lsq[0]); lsq[1] = fmaf(a1, a1, lsq[1]);
    lsq[2] = fmaf(a2, a2, lsq[2]); lsq[3] = fmaf(a3, a3, lsq[3]);
  }

#pragma unroll
  for (int j = 0; j < 4; ++j) {
    float sv = lsum[j], qv = lsq[j];
#pragma unroll
    for (int d = 4; d < 64; d <<= 1) { sv += __shfl_down(sv, d); qv += __shfl_down(qv, d); }
    if (lane < 4) {
      part[(lane * 4 + j) * 4096 + gwave]      = sv;
      part[(16 + lane * 4 + j) * 4096 + gwave] = qv;
    }
  }
}

// ---------------- K9: convT2 (16->1), LDS-tiled, XCD-swizzled --------------
__global__ __launch_bounds__(256) void k_convt2(
    const float* __restrict__ h4, const float* __restrict__ w,
    const float* __restrict__ bias, const float* __restrict__ bnp,
    float* __restrict__ out)
{
  __shared__ float4 s_t[4][18][19];
  __shared__ float s_w[256];     // [ci16][kh4][kw4]
  const int tid = threadIdx.x;
  s_w[tid] = w[tid];

  // bijective XCD swizzle: grid 4096 = 8 * 512
  const int bx = ((blockIdx.x & 7) << 9) | (blockIdx.x >> 3);
  const int n = bx >> 6;
  const int tile = bx & 63;
  const int ta = ((tile >> 3) << 4);
  const int tb = ((tile & 7) << 4);
  const float* hb = h4 + (size_t)n * 262144;

  for (int i = tid; i < 1296; i += 256) {     // 324 positions x 4 groups
    int g = i & 3, p = i >> 2;
    int row = p / 18, col = p - row * 18;
    int ih = ta - 1 + row, iw = tb - 1 + col;
    float4 t = make_float4(0.f, 0.f, 0.f, 0.f);
    if (((unsigned)ih < 128u) && ((unsigned)iw < 128u)) {
      float4 v   = *(const float4*)(hb + ((ih << 7) + iw) * 16 + (g << 2));
      float4 scv = *(const float4*)(bnp + 40 + (g << 2));
      float4 shv = *(const float4*)(bnp + 56 + (g << 2));
      t.x = fmaxf(fmaf(v.x, scv.x, shv.x), 0.f);
      t.y = fmaxf(fmaf(v.y, scv.y, shv.y), 0.f);
      t.z = fmaxf(fmaf(v.z, scv.z, shv.z), 0.f);
      t.w = fmaxf(fmaf(v.w, scv.w, shv.w), 0.f);
    }
    s_t[g][row][col] = t;
  }
  __syncthreads();

  const int a = tid >> 4, b = tid & 15;
  const float4* s_w4 = (const float4*)s_w;
  float acc00 = 0.f, acc01 = 0.f, acc10 = 0.f, acc11 = 0.f;

#pragma unroll
  for (int g = 0; g < 4; ++g) {
    float4 v00 = s_t[g][a  ][b  ], v01 = s_t[g][a  ][b+1], v02 = s_t[g][a  ][b+2];
    float4 v10 = s_t[g][a+1][b  ], v11 = s_t[g][a+1][b+1], v12 = s_t[g][a+1][b+2];
    float4 v20 = s_t[g][a+2][b  ], v21 = s_t[g][a+2][b+1], v22 = s_t[g][a+2][b+2];
#pragma unroll
    for (int j = 0; j < 4; ++j) {
      int ci = g * 4 + j;
      float4 r0 = s_w4[ci*4+0], r1 = s_w4[ci*4+1];
      float4 r2 = s_w4[ci*4+2], r3 = s_w4[ci*4+3];
      float a00 = (j==0)?v00.x:(j==1)?v00.y:(j==2)?v00.z:v00.w;
      float a01 = (j==0)?v01.x:(j==1)?v01.y:(j==2)?v01.z:v01.w;
      float a02 = (j==0)?v02.x:(j==1)?v02.y:(j==2)?v02.z:v02.w;
      float a10 = (j==0)?v10.x:(j==1)?v10.y:(j==2)?v10.z:v10.w;
      float a11 = (j==0)?v11.x:(j==1)?v11.y:(j==2)?v11.z:v11.w;
      float a12 = (j==0)?v12.x:(j==1)?v12.y:(j==2)?v12.z:v12.w;
      float a20 = (j==0)?v20.x:(j==1)?v20.y:(j==2)?v20.z:v20.w;
      float a21 = (j==0)?v21.x:(j==1)?v21.y:(j==2)?v21.z:v21.w;
      float a22 = (j==0)?v22.x:(j==1)?v22.y:(j==2)?v22.z:v22.w;
      acc00 += a00*r0.x + a01*r0.z + a10*r2.x + a11*r2.z;
      acc01 += a01*r0.y + a02*r0.w + a11*r2.y + a12*r2.w;
      acc10 += a10*r1.x + a11*r1.z + a20*r3.x + a21*r3.z;
      acc11 += a11*r1.y + a12*r1.w + a21*r3.y + a22*r3.w;
    }
  }
  const float bv = bias[0];
  const int A = ta + a, B = tb + b;
  float* ob = out + n * 65536 + (2 * A) * 256 + 2 * B;
  *(float2*)ob         = make_float2(acc00 + bv, acc01 + bv);
  *(float2*)(ob + 256) = make_float2(acc10 + bv, acc11 + bv);
}

// ---------------------------------------------------------------------------
extern "C" void kernel_launch(void* const* d_in, const int* in_sizes, int n_in,
                              void* d_out, int out_size, void* d_ws, size_t ws_size,
                              hipStream_t stream)
{
  const float* x      = (const float*)d_in[0];
  const float* enc_w1 = (const float*)d_in[1];
  const float* enc_b1 = (const float*)d_in[2];
  const float* bn1_g  = (const float*)d_in[3];
  const float* bn1_b  = (const float*)d_in[4];
  const float* enc_w2 = (const float*)d_in[5];
  const float* enc_b2 = (const float*)d_in[6];
  const float* bn2_g  = (const float*)d_in[7];
  const float* bn2_b  = (const float*)d_in[8];
  const float* pre_w  = (const float*)d_in[9];
  const float* pre_b  = (const float*)d_in[10];
  const float* cb     = (const float*)d_in[11];
  const float* post_w = (const float*)d_in[12];
  const float* post_b = (const float*)d_in[13];
  const float* dec_w1 = (const float*)d_in[14];
  const float* dec_b1 = (const float*)d_in[15];
  const float* bn3_g  = (const float*)d_in[16];
  const float* bn3_b  = (const float*)d_in[17];
  const float* dec_w2 = (const float*)d_in[18];
  const float* dec_b2 = (const float*)d_in[19];

  float* ws  = (float*)d_ws;
  float* y1  = ws;                       // 16,777,216 f (NHWC) -- reused as h4
  float* y2  = ws + 16777216;            //  1,048,576 f
  float* h3  = ws + 17825792;            //  1,048,576 f
  float* p1  = ws + 18874368;            //    131,072 f ([32][4096]) -- also p3
  float* p2  = ws + 19005440;            //    131,072 f ([8][16384])
  float* lp  = ws + 19136512;            //      1,024 f
  float* bnp = ws + 19137536;            //         72 f (sc1,sh1,sc2,sh2,sc3,sh3)
  float* h4  = y1;
  float* p3  = p1;
  float* out = (float*)d_out;

  k_conv1<<<1024, 256, 0, stream>>>(x, enc_w1, enc_b1, y1, p1);
  k_bnredN<16, 4096><<<16, 256, 0, stream>>>(p1, bn1_g, bn1_b, bnp, bnp + 16, 1.0 / 1048576.0);
  k_conv2<<<4096, 256, 0, stream>>>(y1, enc_w2, enc_b2, bnp, y2, p2);
  k_bnredN<4, 16384><<<4, 256, 0, stream>>>(p2, bn2_g, bn2_b, bnp + 32, bnp + 36, 1.0 / 262144.0);
  k_vq<<<1024, 256, 0, stream>>>(y2, bnp + 32, pre_w, pre_b, cb, post_w, post_b, h3, lp);
  k_lossfin<<<1, 256, 0, stream>>>(lp, out + 4194304);
  k_convt1<<<1024, 256, 0, stream>>>(h3, dec_w1, dec_b1, h4, p3);
  k_bnredN<16, 4096><<<16, 256, 0, stream>>>(p3, bn3_g, bn3_b, bnp + 40, bnp + 56, 1.0 / 1048576.0);
  k_convt2<<<4096, 256, 0, stream>>>(h4, dec_w2, dec_b2, bnp, out);
}

// Round 15
// 135.775 us; speedup vs baseline: 1.1084x; 1.0018x over previous
//
#include <hip/hip_runtime.h>

// ---------------------------------------------------------------------------
// VQ-VAE forward, f32, NHWC intermediates (channels innermost -> float4 I/O).
//  K1 conv1 (1->16) co-split + LDS-staged x patch, P=8 (2048 blk) -> y1
//  K2 bn1 reduce (16 blocks, partials [stat32][8192])
//  K3 conv2 (16->4) co-split (IN-ch quad/lane), XCD-swizzled -> y2
//  K4 bn2 reduce (4 blocks, partials [8][16384])
//  K5 VQ fused -> h3
//  K6 loss finalize -> d_out[4194304]
//  K7 convT1 (4->16) co-split + LDS-staged h3 patch, P=8 (2048 blk) -> h4
//  K8 bn3 reduce (16 blocks)
//  K9 convT2 (16->1), LDS-tiled, XCD-swizzled -> d_out
// R14 lesson: LDS-staging conv1/convt1 reads = neutral -> not read-bound.
// This round: P=16 -> P=8 (2 -> 4 waves/SIMD) to hide the 16 dwordx4 store
// latencies; the only other P tested (P=4, R11) overpaid in stats tails.
// ---------------------------------------------------------------------------

// ---------------- K1: conv1, x staged in LDS, co-split, stats (P=8) --------
// Block = one image x 4 output rows (512 px). Stage 10x258 x-patch once.
__global__ __launch_bounds__(256) void k_conv1(
    const float* __restrict__ x, const float* __restrict__ w1,
    const float* __restrict__ b1, float* __restrict__ y1,
    float* __restrict__ part)
{
  __shared__ float s_x[10 * 260];    // rows 10, stride 260, cols 0..257 used
  __shared__ float s_w[256];         // [k16][c16]
  __shared__ float s_b[16];
  const int tid = threadIdx.x;
  { int c = tid >> 4, k = tid & 15; s_w[k * 16 + c] = w1[c * 16 + k]; }
  if (tid < 16) s_b[tid] = b1[tid];

  const int n  = blockIdx.x >> 5;          // 32 row-blocks per image
  const int rb = blockIdx.x & 31;
  const int ih0 = (rb << 3) - 1;           // input row origin
  const float* xb = x + n * 65536;

  for (int j = tid; j < 2580; j += 256) {  // 10 * 258
    int rr = j / 258, c = j - rr * 258;
    int ih = ih0 + rr, iw = c - 1;
    float v = 0.f;
    if (((unsigned)ih < 256u) && ((unsigned)iw < 256u)) v = xb[ih * 256 + iw];
    s_x[rr * 260 + c] = v;
  }
  __syncthreads();

  const int lane = tid & 63;
  const int cb = lane & 3;                 // out-channel quad
  const int psl = lane >> 2;               // pixel slot 0..15
  const int gwave = (blockIdx.x << 2) | (tid >> 6);   // 8192 waves
  const int base = gwave << 7;             // 128 consecutive pixels per wave
  const float4* s_w4 = (const float4*)s_w;
  const float4 bv = ((const float4*)s_b)[cb];

  float lsum[4] = {0.f, 0.f, 0.f, 0.f}, lsq[4] = {0.f, 0.f, 0.f, 0.f};

#pragma unroll 1
  for (int i = 0; i < 8; ++i) {
    const int pos = base + (i << 4) + psl;
    const int r = pos & 16383;
    const int oh = r >> 7, ow = r & 127;
    const int lr2 = (oh - (rb << 2)) << 1;     // 2 * local output row

    float a0 = bv.x, a1 = bv.y, a2 = bv.z, a3 = bv.w;
#pragma unroll
    for (int kh = 0; kh < 4; ++kh) {
      const float* rowp = s_x + (lr2 + kh) * 260 + (ow << 1);
#pragma unroll
      for (int kw = 0; kw < 4; ++kw) {
        float v = rowp[kw];
        float4 wv = s_w4[(kh * 4 + kw) * 4 + cb];
        a0 = fmaf(v, wv.x, a0); a1 = fmaf(v, wv.y, a1);
        a2 = fmaf(v, wv.z, a2); a3 = fmaf(v, wv.w, a3);
      }
    }
    *(float4*)(y1 + (size_t)pos * 16 + cb * 4) = make_float4(a0, a1, a2, a3);
    lsum[0] += a0; lsum[1] += a1; lsum[2] += a2; lsum[3] += a3;
    lsq[0] = fmaf(a0, a0, lsq[0]); lsq[1] = fmaf(a1, a1, lsq[1]);
    lsq[2] = fmaf(a2, a2, lsq[2]); lsq[3] = fmaf(a3, a3, lsq[3]);
  }

#pragma unroll
  for (int j = 0; j < 4; ++j) {
    float sv = lsum[j], qv = lsq[j];
#pragma unroll
    for (int d = 4; d < 64; d <<= 1) { sv += __shfl_down(sv, d); qv += __shfl_down(qv, d); }
    if (lane < 4) {
      part[(lane * 4 + j) * 8192 + gwave]      = sv;
      part[(16 + lane * 4 + j) * 8192 + gwave] = qv;
    }
  }
}

// ---------------- BN reduce: NCH blocks, NW per-wave partials --------------
template <int NCH, int NW>
__global__ __launch_bounds__(256) void k_bnredN(
    const float* __restrict__ part, const float* __restrict__ g,
    const float* __restrict__ bt, float* __restrict__ sc,
    float* __restrict__ sh, double invN)
{
  __shared__ double sd[256], sqd[256];
  const int c = blockIdx.x, tid = threadIdx.x;
  const float4* ps = (const float4*)(part + (size_t)c * NW);
  const float4* pq = (const float4*)(part + (size_t)(NCH + c) * NW);
  double S = 0.0, Q = 0.0;
#pragma unroll
  for (int i = 0; i < NW / 1024; ++i) {
    float4 v = ps[i * 256 + tid];
    S += (double)v.x + (double)v.y + (double)v.z + (double)v.w;
    float4 q = pq[i * 256 + tid];
    Q += (double)q.x + (double)q.y + (double)q.z + (double)q.w;
  }
  sd[tid] = S; sqd[tid] = Q;
  __syncthreads();
  for (int off = 128; off > 0; off >>= 1) {
    if (tid < off) { sd[tid] += sd[tid + off]; sqd[tid] += sqd[tid + off]; }
    __syncthreads();
  }
  if (tid == 0) {
    double mean = sd[0] * invN;
    double var  = sqd[0] * invN - mean * mean;
    float scale = (float)((double)g[c] / sqrt(var + 1e-5));
    sc[c] = scale;
    sh[c] = bt[c] - (float)mean * scale;
  }
}

// ---------------- K3: conv2 co-split over INPUT channels (R11-proven) ------
__global__ __launch_bounds__(256) void k_conv2(
    const float* __restrict__ y1, const float* __restrict__ w2,
    const float* __restrict__ b2, const float* __restrict__ bnp,
    float* __restrict__ y2, float* __restrict__ part)
{
  __shared__ float s_w[1024];        // [k16][ci16][co4]
  __shared__ float s_sc[16], s_sh[16];
  __shared__ float s_b[4];
  const int tid = threadIdx.x;
  for (int i = tid; i < 1024; i += 256) {
    int co = i & 3, ci = (i >> 2) & 15, k = i >> 6;
    int kh = k >> 2, kw = k & 3;
    s_w[i] = w2[((co * 16 + ci) * 4 + kh) * 4 + kw];
  }
  if (tid < 16) { s_sc[tid] = bnp[tid]; s_sh[tid] = bnp[16 + tid]; }
  if (tid < 4)  s_b[tid] = b2[tid];
  __syncthreads();

  // bijective XCD swizzle: grid 4096 = 8 * 512
  const int bid = ((blockIdx.x & 7) << 9) | (blockIdx.x >> 3);
  const int lane = tid & 63;
  const int cb = lane & 3;                 // input-channel quad
  const int psl = lane >> 2;               // pixel slot 0..15
  const int gwave = (bid << 2) | (tid >> 6);   // 16384 waves
  const int pos = (gwave << 4) + psl;          // < 262,144
  const int n = pos >> 12, r = pos & 4095;
  const int oh = r >> 6, ow = r & 63;
  const int ihb = oh * 2 - 1, iwb = ow * 2 - 1;
  const float* yb = y1 + (size_t)n * 262144;
  const float4* s_w4 = (const float4*)s_w;
  const float4 scv = ((const float4*)s_sc)[cb];
  const float4 shv = ((const float4*)s_sh)[cb];

  float acc0 = 0.f, acc1 = 0.f, acc2 = 0.f, acc3 = 0.f;

#pragma unroll
  for (int kh = 0; kh < 4; ++kh) {
    int ih = ihb + kh; bool okh = (unsigned)ih < 128u;
#pragma unroll
    for (int kw = 0; kw < 4; ++kw) {
      int iw = iwb + kw;
      bool ok = okh && ((unsigned)iw < 128u);
      if (ok) {
        float4 v = *(const float4*)(yb + (ih * 128 + iw) * 16 + (cb << 2));
        float a0 = fmaxf(fmaf(v.x, scv.x, shv.x), 0.f);
        float a1 = fmaxf(fmaf(v.y, scv.y, shv.y), 0.f);
        float a2 = fmaxf(fmaf(v.z, scv.z, shv.z), 0.f);
        float a3 = fmaxf(fmaf(v.w, scv.w, shv.w), 0.f);
        int kb = (((kh << 2) | kw) << 4) + (cb << 2);
        float4 w0 = s_w4[kb + 0];
        float4 w1 = s_w4[kb + 1];
        float4 w2v = s_w4[kb + 2];
        float4 w3 = s_w4[kb + 3];
        acc0 = fmaf(a0, w0.x, fmaf(a1, w1.x, fmaf(a2, w2v.x, fmaf(a3, w3.x, acc0))));
        acc1 = fmaf(a0, w0.y, fmaf(a1, w1.y, fmaf(a2, w2v.y, fmaf(a3, w3.y, acc1))));
        acc2 = fmaf(a0, w0.z, fmaf(a1, w1.z, fmaf(a2, w2v.z, fmaf(a3, w3.z, acc2))));
        acc3 = fmaf(a0, w0.w, fmaf(a1, w1.w, fmaf(a2, w2v.w, fmaf(a3, w3.w, acc3))));
      }
    }
  }
  acc0 += __shfl_xor(acc0, 1); acc0 += __shfl_xor(acc0, 2);
  acc1 += __shfl_xor(acc1, 1); acc1 += __shfl_xor(acc1, 2);
  acc2 += __shfl_xor(acc2, 1); acc2 += __shfl_xor(acc2, 2);
  acc3 += __shfl_xor(acc3, 1); acc3 += __shfl_xor(acc3, 2);
  acc0 += s_b[0]; acc1 += s_b[1]; acc2 += s_b[2]; acc3 += s_b[3];

  if (cb == 0)
    *(float4*)(y2 + (size_t)pos * 4) = make_float4(acc0, acc1, acc2, acc3);

  float ls[4] = {acc0, acc1, acc2, acc3};
#pragma unroll
  for (int c = 0; c < 4; ++c) {
    float sv = ls[c], qv = ls[c] * ls[c];
#pragma unroll
    for (int d = 4; d < 64; d <<= 1) { sv += __shfl_down(sv, d); qv += __shfl_down(qv, d); }
    if (lane == 0) {
      part[c * 16384 + gwave]       = sv;
      part[(4 + c) * 16384 + gwave] = qv;
    }
  }
}

// ---------------- K5: fused VQ -------------------------------------------
__global__ __launch_bounds__(256) void k_vq(
    const float* __restrict__ y2, const float* __restrict__ bnp2,
    const float* __restrict__ pw, const float* __restrict__ pb,
    const float* __restrict__ cb, const float* __restrict__ postw,
    const float* __restrict__ postb, float* __restrict__ h3,
    float* __restrict__ lpart)
{
  const int tid = threadIdx.x;
  const int pos = blockIdx.x * 256 + tid;     // < 262,144
  float4 v = *(const float4*)(y2 + (size_t)pos * 4);
  float aa0 = fmaxf(fmaf(v.x, bnp2[0], bnp2[4]), 0.f);
  float aa1 = fmaxf(fmaf(v.y, bnp2[1], bnp2[5]), 0.f);
  float aa2 = fmaxf(fmaf(v.z, bnp2[2], bnp2[6]), 0.f);
  float aa3 = fmaxf(fmaf(v.w, bnp2[3], bnp2[7]), 0.f);
  float z0 = pb[0] + aa0*pw[0] + aa1*pw[1] + aa2*pw[2] + aa3*pw[3];
  float z1 = pb[1] + aa0*pw[4] + aa1*pw[5] + aa2*pw[6] + aa3*pw[7];

  float best = 3.4e38f, q0 = 0.f, q1 = 0.f;
#pragma unroll
  for (int k = 0; k < 3; ++k) {
    float c0 = cb[2 * k], c1 = cb[2 * k + 1];
    float dx = z0 - c0, dy = z1 - c1;
    float d = dx * dx + dy * dy;
    if (d < best) { best = d; q0 = c0; q1 = c1; }   // strict < == first-min
  }
  float dl = (q0 - z0) * (q0 - z0) + (q1 - z1) * (q1 - z1);

  float4 hv;
  hv.x = fmaf(q0, postw[0], fmaf(q1, postw[1], postb[0]));
  hv.y = fmaf(q0, postw[2], fmaf(q1, postw[3], postb[1]));
  hv.z = fmaf(q0, postw[4], fmaf(q1, postw[5], postb[2]));
  hv.w = fmaf(q0, postw[6], fmaf(q1, postw[7], postb[3]));
  *(float4*)(h3 + (size_t)pos * 4) = hv;

  float s = dl;
#pragma unroll
  for (int d = 32; d > 0; d >>= 1) s += __shfl_down(s, d);
  __shared__ float ws4[4];
  if ((tid & 63) == 0) ws4[tid >> 6] = s;
  __syncthreads();
  if (tid == 0) lpart[blockIdx.x] = (ws4[0] + ws4[1]) + (ws4[2] + ws4[3]);
}

__global__ __launch_bounds__(256) void k_lossfin(
    const float* __restrict__ lpart, float* __restrict__ outp)
{
  const int tid = threadIdx.x;
  float s = lpart[tid] + lpart[tid + 256] + lpart[tid + 512] + lpart[tid + 768];
#pragma unroll
  for (int d = 32; d > 0; d >>= 1) s += __shfl_down(s, d);
  __shared__ float ws4[4];
  if ((tid & 63) == 0) ws4[tid >> 6] = s;
  __syncthreads();
  if (tid == 0) {
    double tot = (double)ws4[0] + (double)ws4[1] + (double)ws4[2] + (double)ws4[3];
    outp[0] = (float)(1.2 * tot / 524288.0);   // (1+BETA) * mean over B*N*C
  }
}

// ---------------- K7: convT1 (4->16), h3 staged in LDS, co-split (P=8) -----
// Block = one image x 4 output rows (512 px). Stage 4x66 float4 h3-patch.
__global__ __launch_bounds__(256) void k_convt1(
    const float* __restrict__ h3, const float* __restrict__ w,
    const float* __restrict__ bias, float* __restrict__ h4,
    float* __restrict__ part)
{
  __shared__ float4 s_h[4 * 68];     // 4 rows, stride 68, cols 0..65 used
  __shared__ float s_w[1024];        // [k16][ci4][co16]
  __shared__ float s_b[16];
  const int tid = threadIdx.x;
  for (int i = tid; i < 1024; i += 256) {
    int co = i & 15, ci = (i >> 4) & 3, k = i >> 6;
    int kh = k >> 2, kw = k & 3;
    s_w[i] = w[((co * 4 + ci) * 4 + kh) * 4 + kw];
  }
  if (tid < 16) s_b[tid] = bias[tid];

  const int n  = blockIdx.x >> 5;          // 32 row-blocks per image
  const int rb = blockIdx.x & 31;
  const int row0 = (rb << 1) - 1;          // h3 row origin
  const float* hb = h3 + (size_t)n * 16384;

  for (int j = tid; j < 264; j += 256) {   // 4 * 66
    int rr = j / 66, c = j - rr * 66;
    int sr = row0 + rr, sc = c - 1;
    float4 t = make_float4(0.f, 0.f, 0.f, 0.f);
    if (((unsigned)sr < 64u) && ((unsigned)sc < 64u))
      t = *(const float4*)(hb + (sr * 64 + sc) * 4);
    s_h[rr * 68 + c] = t;
  }
  __syncthreads();

  const int lane = tid & 63;
  const int cb = lane & 3;
  const int psl = lane >> 2;
  const int gwave = (blockIdx.x << 2) | (tid >> 6);   // 8192 waves
  const int base = gwave << 7;             // 128 pixels per wave
  const float4* s_w4 = (const float4*)s_w;   // idx = k*16 + ci*4 + cb
  const float4 bv = ((const float4*)s_b)[cb];

  float lsum[4] = {0.f, 0.f, 0.f, 0.f}, lsq[4] = {0.f, 0.f, 0.f, 0.f};

#pragma unroll 1
  for (int i = 0; i < 8; ++i) {
    const int pos = base + (i << 4) + psl;
    const int r = pos & 16383;
    const int oh = r >> 7, ow = r & 127;
    const int ohp = oh & 1, owp = ow & 1;

    float a0 = bv.x, a1 = bv.y, a2 = bv.z, a3 = bv.w;
#pragma unroll
    for (int th = 0; th < 2; ++th) {
      int kh = th * 2 + ohp;
      int lih = ((oh + kh - 2) >> 1) - row0;
#pragma unroll
      for (int tw = 0; tw < 2; ++tw) {
        int kw = tw * 2 + owp;
        int liw = ((ow + kw - 2) >> 1) + 1;
        float4 v = s_h[lih * 68 + liw];
        int k16 = (kh * 4 + kw) * 16;
        float4 w0 = s_w4[k16 + 0 * 4 + cb];
        float4 w1 = s_w4[k16 + 1 * 4 + cb];
        float4 w2 = s_w4[k16 + 2 * 4 + cb];
        float4 w3 = s_w4[k16 + 3 * 4 + cb];
        a0 = fmaf(v.x, w0.x, fmaf(v.y, w1.x, fmaf(v.z, w2.x, fmaf(v.w, w3.x, a0))));
        a1 = fmaf(v.x, w0.y, fmaf(v.y, w1.y, fmaf(v.z, w2.y, fmaf(v.w, w3.y, a1))));
        a2 = fmaf(v.x, w0.z, fmaf(v.y, w1.z, fmaf(v.z, w2.z, fmaf(v.w, w3.z, a2))));
        a3 = fmaf(v.x, w0.w, fmaf(v.y, w1.w, fmaf(v.z, w2.w, fmaf(v.w, w3.w, a3))));
      }
    }
    *(float4*)(h4 + (size_t)pos * 16 + cb * 4) = make_float4(a0, a1, a2, a3);
    lsum[0] += a0; lsum[1] += a1; lsum[2] += a2; lsum[3] += a3;
    lsq[0] = fmaf(a0, a0, lsq[0]); lsq[1] = fmaf(a1, a1, lsq[1]);
    lsq[2] = fmaf(a2, a2, lsq[2]); lsq[3] = fmaf(a3, a3, lsq[3]);
  }

#pragma unroll
  for (int j = 0; j < 4; ++j) {
    float sv = lsum[j], qv = lsq[j];
#pragma unroll
    for (int d = 4; d < 64; d <<= 1) { sv += __shfl_down(sv, d); qv += __shfl_down(qv, d); }
    if (lane < 4) {
      part[(lane * 4 + j) * 8192 + gwave]      = sv;
      part[(16 + lane * 4 + j) * 8192 + gwave] = qv;
    }
  }
}

// ---------------- K9: convT2 (16->1), LDS-tiled, XCD-swizzled --------------
__global__ __launch_bounds__(256) void k_convt2(
    const float* __restrict__ h4, const float* __restrict__ w,
    const float* __restrict__ bias, const float* __restrict__ bnp,
    float* __restrict__ out)
{
  __shared__ float4 s_t[4][18][19];
  __shared__ float s_w[256];     // [ci16][kh4][kw4]
  const int tid = threadIdx.x;
  s_w[tid] = w[tid];

  // bijective XCD swizzle: grid 4096 = 8 * 512
  const int bx = ((blockIdx.x & 7) << 9) | (blockIdx.x >> 3);
  const int n = bx >> 6;
  const int tile = bx & 63;
  const int ta = ((tile >> 3) << 4);
  const int tb = ((tile & 7) << 4);
  const float* hb = h4 + (size_t)n * 262144;

  for (int i = tid; i < 1296; i += 256) {     // 324 positions x 4 groups
    int g = i & 3, p = i >> 2;
    int row = p / 18, col = p - row * 18;
    int ih = ta - 1 + row, iw = tb - 1 + col;
    float4 t = make_float4(0.f, 0.f, 0.f, 0.f);
    if (((unsigned)ih < 128u) && ((unsigned)iw < 128u)) {
      float4 v   = *(const float4*)(hb + ((ih << 7) + iw) * 16 + (g << 2));
      float4 scv = *(const float4*)(bnp + 40 + (g << 2));
      float4 shv = *(const float4*)(bnp + 56 + (g << 2));
      t.x = fmaxf(fmaf(v.x, scv.x, shv.x), 0.f);
      t.y = fmaxf(fmaf(v.y, scv.y, shv.y), 0.f);
      t.z = fmaxf(fmaf(v.z, scv.z, shv.z), 0.f);
      t.w = fmaxf(fmaf(v.w, scv.w, shv.w), 0.f);
    }
    s_t[g][row][col] = t;
  }
  __syncthreads();

  const int a = tid >> 4, b = tid & 15;
  const float4* s_w4 = (const float4*)s_w;
  float acc00 = 0.f, acc01 = 0.f, acc10 = 0.f, acc11 = 0.f;

#pragma unroll
  for (int g = 0; g < 4; ++g) {
    float4 v00 = s_t[g][a  ][b  ], v01 = s_t[g][a  ][b+1], v02 = s_t[g][a  ][b+2];
    float4 v10 = s_t[g][a+1][b  ], v11 = s_t[g][a+1][b+1], v12 = s_t[g][a+1][b+2];
    float4 v20 = s_t[g][a+2][b  ], v21 = s_t[g][a+2][b+1], v22 = s_t[g][a+2][b+2];
#pragma unroll
    for (int j = 0; j < 4; ++j) {
      int ci = g * 4 + j;
      float4 r0 = s_w4[ci*4+0], r1 = s_w4[ci*4+1];
      float4 r2 = s_w4[ci*4+2], r3 = s_w4[ci*4+3];
      float a00 = (j==0)?v00.x:(j==1)?v00.y:(j==2)?v00.z:v00.w;
      float a01 = (j==0)?v01.x:(j==1)?v01.y:(j==2)?v01.z:v01.w;
      float a02 = (j==0)?v02.x:(j==1)?v02.y:(j==2)?v02.z:v02.w;
      float a10 = (j==0)?v10.x:(j==1)?v10.y:(j==2)?v10.z:v10.w;
      float a11 = (j==0)?v11.x:(j==1)?v11.y:(j==2)?v11.z:v11.w;
      float a12 = (j==0)?v12.x:(j==1)?v12.y:(j==2)?v12.z:v12.w;
      float a20 = (j==0)?v20.x:(j==1)?v20.y:(j==2)?v20.z:v20.w;
      float a21 = (j==0)?v21.x:(j==1)?v21.y:(j==2)?v21.z:v21.w;
      float a22 = (j==0)?v22.x:(j==1)?v22.y:(j==2)?v22.z:v22.w;
      acc00 += a00*r0.x + a01*r0.z + a10*r2.x + a11*r2.z;
      acc01 += a01*r0.y + a02*r0.w + a11*r2.y + a12*r2.w;
      acc10 += a10*r1.x + a11*r1.z + a20*r3.x + a21*r3.z;
      acc11 += a11*r1.y + a12*r1.w + a21*r3.y + a22*r3.w;
    }
  }
  const float bv = bias[0];
  const int A = ta + a, B = tb + b;
  float* ob = out + n * 65536 + (2 * A) * 256 + 2 * B;
  *(float2*)ob         = make_float2(acc00 + bv, acc01 + bv);
  *(float2*)(ob + 256) = make_float2(acc10 + bv, acc11 + bv);
}

// ---------------------------------------------------------------------------
extern "C" void kernel_launch(void* const* d_in, const int* in_sizes, int n_in,
                              void* d_out, int out_size, void* d_ws, size_t ws_size,
                              hipStream_t stream)
{
  const float* x      = (const float*)d_in[0];
  const float* enc_w1 = (const float*)d_in[1];
  const float* enc_b1 = (const float*)d_in[2];
  const float* bn1_g  = (const float*)d_in[3];
  const float* bn1_b  = (const float*)d_in[4];
  const float* enc_w2 = (const float*)d_in[5];
  const float* enc_b2 = (const float*)d_in[6];
  const float* bn2_g  = (const float*)d_in[7];
  const float* bn2_b  = (const float*)d_in[8];
  const float* pre_w  = (const float*)d_in[9];
  const float* pre_b  = (const float*)d_in[10];
  const float* cb     = (const float*)d_in[11];
  const float* post_w = (const float*)d_in[12];
  const float* post_b = (const float*)d_in[13];
  const float* dec_w1 = (const float*)d_in[14];
  const float* dec_b1 = (const float*)d_in[15];
  const float* bn3_g  = (const float*)d_in[16];
  const float* bn3_b  = (const float*)d_in[17];
  const float* dec_w2 = (const float*)d_in[18];
  const float* dec_b2 = (const float*)d_in[19];

  float* ws  = (float*)d_ws;
  float* y1  = ws;                       // 16,777,216 f (NHWC) -- reused as h4
  float* y2  = ws + 16777216;            //  1,048,576 f
  float* h3  = ws + 17825792;            //  1,048,576 f
  float* p1  = ws + 18874368;            //    262,144 f ([32][8192]) -- also p3
  float* p2  = ws + 19136512;            //    131,072 f ([8][16384])
  float* lp  = ws + 19267584;            //      1,024 f
  float* bnp = ws + 19268608;            //         72 f (sc1,sh1,sc2,sh2,sc3,sh3)
  float* h4  = y1;
  float* p3  = p1;
  float* out = (float*)d_out;

  k_conv1<<<2048, 256, 0, stream>>>(x, enc_w1, enc_b1, y1, p1);
  k_bnredN<16, 8192><<<16, 256, 0, stream>>>(p1, bn1_g, bn1_b, bnp, bnp + 16, 1.0 / 1048576.0);
  k_conv2<<<4096, 256, 0, stream>>>(y1, enc_w2, enc_b2, bnp, y2, p2);
  k_bnredN<4, 16384><<<4, 256, 0, stream>>>(p2, bn2_g, bn2_b, bnp + 32, bnp + 36, 1.0 / 262144.0);
  k_vq<<<1024, 256, 0, stream>>>(y2, bnp + 32, pre_w, pre_b, cb, post_w, post_b, h3, lp);
  k_lossfin<<<1, 256, 0, stream>>>(lp, out + 4194304);
  k_convt1<<<2048, 256, 0, stream>>>(h3, dec_w1, dec_b1, h4, p3);
  k_bnredN<16, 8192><<<16, 256, 0, stream>>>(p3, bn3_g, bn3_b, bnp + 40, bnp + 56, 1.0 / 1048576.0);
  k_convt2<<<4096, 256, 0, stream>>>(h4, dec_w2, dec_b2, bnp, out);
}